// Round 1
// baseline (10589.560 us; speedup 1.0000x reference)
//
#include <hip/hip_runtime.h>
#include <math.h>

// POSTagEncoder: expert-routed linear -> 1-layer LSTM (i,f,g,o) -> time max-pool.
// S=8192 tokens, D=128, E=48 experts. Output [1,128] fp32.
//
// Kernel 1 (build_xg): fully parallel. Per token: z = W_exp[e] @ emb + b_exp[e];
//                      xg = W_ih @ z + b_ih + b_hh  -> workspace [8192][512].
// Kernel 2 (lstm_scan): single block of 256 threads (4 waves) on one CU.
//   - W_hh register-resident: lane holds rows G (i/f) and G+256 (g/o), 256 floats.
//   - h kept redundantly per wave as float2/lane; broadcast via v_readlane (no LDS
//     broadcast reads -- those would cost ~3000 LDS-pipe cyc/step on CDNA).
//   - gate exchange via double-buffered LDS, ONE __syncthreads per step.

#define SEQ   8192
#define DIM   128
#define NGATE 512   // 4*DIM

__device__ __forceinline__ float sigm_fast(float x) {
    // 1/(1+exp(-x)); inf-safe at both ends
    return __fdividef(1.0f, 1.0f + __expf(-x));
}
__device__ __forceinline__ float tanh_fast(float x) {
    // tanh(x) = 1 - 2/(exp(2x)+1); exp overflow -> inf -> 1, exp->0 -> -1
    float e = __expf(2.0f * x);
    return 1.0f - __fdividef(2.0f, e + 1.0f);
}

__device__ __forceinline__ float rdlane(float v, int lane) {
    return __uint_as_float(__builtin_amdgcn_readlane(__float_as_uint(v), lane));
}

// ---------------------------------------------------------------------------
// Kernel 1: per-token expert GEMV + input-side gate GEMM
// grid = SEQ blocks, 128 threads
// ---------------------------------------------------------------------------
__global__ __launch_bounds__(128) void build_xg(
    const float* __restrict__ embs, const int* __restrict__ pos_ids,
    const float* __restrict__ W_exp, const float* __restrict__ b_exp,
    const float* __restrict__ W_ih, const float* __restrict__ b_ih,
    const float* __restrict__ b_hh, float* __restrict__ xg)
{
    __shared__ float4 embv[DIM / 4];
    __shared__ float4 zv[DIM / 4];
    const int s = blockIdx.x;
    const int i = threadIdx.x;

    if (i < DIM / 4)
        embv[i] = ((const float4*)(embs + (size_t)s * DIM))[i];
    const int e = pos_ids[s];
    __syncthreads();

    // z[i] = b_exp[e][i] + dot(W_exp[e][i][:], emb)
    {
        const float4* Wr = (const float4*)(W_exp + ((size_t)(e * DIM + i)) * DIM);
        float acc = b_exp[e * DIM + i];
        #pragma unroll
        for (int j = 0; j < DIM / 4; ++j) {
            float4 w = Wr[j], x = embv[j];
            acc = fmaf(w.x, x.x, acc); acc = fmaf(w.y, x.y, acc);
            acc = fmaf(w.z, x.z, acc); acc = fmaf(w.w, x.w, acc);
        }
        ((float*)zv)[i] = acc;
    }
    __syncthreads();

    // xg[s][r] = b_ih[r] + b_hh[r] + dot(W_ih[r][:], z)   for r = i + q*128
    float* xgs = xg + (size_t)s * NGATE;
    #pragma unroll
    for (int q = 0; q < 4; ++q) {
        const int r = i + q * DIM;
        const float4* Wr = (const float4*)(W_ih + (size_t)r * DIM);
        float acc = b_ih[r] + b_hh[r];
        #pragma unroll
        for (int j = 0; j < DIM / 4; ++j) {
            float4 w = Wr[j], x = zv[j];
            acc = fmaf(w.x, x.x, acc); acc = fmaf(w.y, x.y, acc);
            acc = fmaf(w.z, x.z, acc); acc = fmaf(w.w, x.w, acc);
        }
        xgs[r] = acc;
    }
}

// ---------------------------------------------------------------------------
// Kernel 2: sequential LSTM scan + max-pool. ONE block, 256 threads (4 waves).
// ---------------------------------------------------------------------------
__global__ __launch_bounds__(256, 1) void lstm_scan(
    const float* __restrict__ xg, const float* __restrict__ W_hh,
    float* __restrict__ out)
{
    const int G = threadIdx.x;     // 0..255
    const int L = G & 63;          // lane in wave
    const int row0 = G;            // i-gate rows 0..127, f-gate rows 128..255
    const int row1 = G + 256;      // g-gate rows 256..383, o-gate rows 384..511

    __shared__ float gbuf[2][NGATE];   // double-buffered activated gates

    // W_hh rows -> registers (fully unrolled constant indexing => VGPR/AGPR file)
    float w0[DIM];
    float w1[DIM];
    {
        const float4* r0 = (const float4*)(W_hh + (size_t)row0 * DIM);
        const float4* r1 = (const float4*)(W_hh + (size_t)row1 * DIM);
        #pragma unroll
        for (int k = 0; k < DIM / 4; ++k) {
            float4 a = r0[k];
            w0[4*k+0] = a.x; w0[4*k+1] = a.y; w0[4*k+2] = a.z; w0[4*k+3] = a.w;
            float4 b = r1[k];
            w1[4*k+0] = b.x; w1[4*k+1] = b.y; w1[4*k+2] = b.z; w1[4*k+3] = b.w;
        }
    }

    // Redundant per-wave state: lane L holds dims 2L, 2L+1
    float2 hv  = {0.0f, 0.0f};
    float2 cv  = {0.0f, 0.0f};
    float2 hmx = {-INFINITY, -INFINITY};

    float xg0 = xg[row0];
    float xg1 = xg[row1];

    for (int t = 0; t < SEQ; ++t) {
        // prefetch next step's xg (latency hidden under the dot product)
        const int tn = (t + 1 < SEQ) ? (t + 1) : t;
        const float xg0n = xg[(size_t)tn * NGATE + row0];
        const float xg1n = xg[(size_t)tn * NGATE + row1];

        // gates pre-activation: acc_r = dot(W_hh[r], h)
        // h[j] broadcast in-register: readlane -> SGPR feeds 2 fmacs (rows 0,1)
        float a0a = 0.0f, a0b = 0.0f, a1a = 0.0f, a1b = 0.0f;
        #pragma unroll
        for (int j2 = 0; j2 < 64; ++j2) {
            const float s0 = rdlane(hv.x, j2);   // h[2*j2]
            const float s1 = rdlane(hv.y, j2);   // h[2*j2+1]
            const int j0 = 2 * j2, j1 = 2 * j2 + 1;
            if (j2 & 1) {
                a0b = fmaf(w0[j0], s0, a0b); a0b = fmaf(w0[j1], s1, a0b);
                a1b = fmaf(w1[j0], s0, a1b); a1b = fmaf(w1[j1], s1, a1b);
            } else {
                a0a = fmaf(w0[j0], s0, a0a); a0a = fmaf(w0[j1], s1, a0a);
                a1a = fmaf(w1[j0], s0, a1a); a1a = fmaf(w1[j1], s1, a1a);
            }
        }
        const float p0 = xg0 + a0a + a0b;
        const float p1 = xg1 + a1a + a1b;

        // activations: row0 is always i or f (sigmoid); row1 is g (tanh, waves 0-1)
        // or o (sigmoid, waves 2-3) -- wave-uniform branch, no divergence
        const float act0 = sigm_fast(p0);
        const float act1 = (G < 128) ? tanh_fast(p1) : sigm_fast(p1);

        float* gb = gbuf[t & 1];
        gb[row0] = act0;
        gb[row1] = act1;
        __syncthreads();   // single barrier per step (double-buffered gbuf)

        // every wave redundantly updates c,h for dims 2L, 2L+1
        const float2 iv = *(const float2*)(gb + 0   + 2 * L);
        const float2 fv = *(const float2*)(gb + 128 + 2 * L);
        const float2 gv = *(const float2*)(gb + 256 + 2 * L);
        const float2 ov = *(const float2*)(gb + 384 + 2 * L);

        cv.x = fmaf(fv.x, cv.x, iv.x * gv.x);
        cv.y = fmaf(fv.y, cv.y, iv.y * gv.y);
        hv.x = ov.x * tanh_fast(cv.x);
        hv.y = ov.y * tanh_fast(cv.y);

        hmx.x = fmaxf(hmx.x, hv.x);
        hmx.y = fmaxf(hmx.y, hv.y);

        xg0 = xg0n; xg1 = xg1n;
    }

    // all waves hold identical hmx; wave 0 writes out[1][128]
    if (G < 64) ((float2*)out)[L] = hmx;
}

// ---------------------------------------------------------------------------
extern "C" void kernel_launch(void* const* d_in, const int* in_sizes, int n_in,
                              void* d_out, int out_size, void* d_ws, size_t ws_size,
                              hipStream_t stream)
{
    const float* embs  = (const float*)d_in[0];
    const int*   pos   = (const int*)  d_in[1];
    const float* W_exp = (const float*)d_in[2];
    const float* b_exp = (const float*)d_in[3];
    const float* W_ih  = (const float*)d_in[4];
    const float* W_hh  = (const float*)d_in[5];
    const float* b_ih  = (const float*)d_in[6];
    const float* b_hh  = (const float*)d_in[7];
    float* out = (float*)d_out;
    float* xg  = (float*)d_ws;   // [SEQ][512] = 16 MB scratch

    build_xg<<<SEQ, 128, 0, stream>>>(embs, pos, W_exp, b_exp, W_ih, b_ih, b_hh, xg);
    lstm_scan<<<1, 256, 0, stream>>>(xg, W_hh, out);
}

// Round 2
// 5778.703 us; speedup vs baseline: 1.8325x; 1.8325x over previous
//
#include <hip/hip_runtime.h>
#include <math.h>

// POSTagEncoder: expert-routed linear -> 1-layer LSTM (i,f,g,o) -> time max-pool.
// S=8192, D=128, E=48. Output [1,128] fp32.
//
// K1a expert_gemv: per-(expert,slice) blocks; W_exp[e] staged coalesced into LDS
//     (XOR-swizzled, conflict-free b128); tokens found via ballot scan.
//     z written into xg[s*512 + 0..128) (in-place, no extra workspace).
// K1b gate_gemm: 32-token tiles; z + W_ih chunks staged coalesced in LDS;
//     writes full xg[s][512].
// K2 lstm_scan: 1 block, 256 threads (4 waves, 1/SIMD). W_hh packed fp16 in
//     VGPRs (128 half2 regs/thread -- under the 256 arch-VGPR limit, unlike the
//     fp32 version which silently went to AGPR/scratch at VGPR_Count=140).
//     h broadcast via readlane of a packed half2; v_dot2_f32_f16 accumulates
//     in fp32. One __syncthreads per step (double-buffered gate LDS).

#define SEQ   8192
#define DIM   128
#define NGATE 512
#define NEXP  48

typedef _Float16 half2v __attribute__((ext_vector_type(2)));

__device__ __forceinline__ float sigm_fast(float x) {
    return __fdividef(1.0f, 1.0f + __expf(-x));   // inf-safe both ends
}
__device__ __forceinline__ float tanh_fast(float x) {
    float e = __expf(2.0f * x);
    return 1.0f - __fdividef(2.0f, e + 1.0f);     // +-1 at saturation
}
__device__ __forceinline__ half2v pack2(float x, float y) {
    half2v r; r.x = (_Float16)x; r.y = (_Float16)y; return r;  // RNE converts
}

// ---------------------------------------------------------------------------
// K1a: z[s] = W_exp[pos_ids[s]] @ embs[s] + b_exp  -> xg[s*512 + 0..128)
// grid = 48 experts * 8 slices, 64 threads (1 wave)
// ---------------------------------------------------------------------------
__global__ __launch_bounds__(64) void expert_gemv(
    const float* __restrict__ embs, const int* __restrict__ pos_ids,
    const float* __restrict__ W_exp, const float* __restrict__ b_exp,
    float* __restrict__ xg)
{
    __shared__ float Wl[DIM * DIM];          // 64KB, rows XOR-swizzled
    const int e     = blockIdx.x % NEXP;
    const int slice = blockIdx.x / NEXP;     // 0..7
    const int tid   = threadIdx.x;           // 0..63

    // coalesced W_exp[e] -> LDS; float4 group c4 of row r stored at (c4 ^ (r&31))
    const float4* Wg = (const float4*)(W_exp + (size_t)e * DIM * DIM);
    #pragma unroll 4
    for (int it = 0; it < 64; ++it) {
        int idx = it * 64 + tid;             // 0..4095 float4s
        int r = idx >> 5, c4 = idx & 31;
        float4 v = Wg[idx];
        *(float4*)&Wl[r * DIM + (((c4 ^ (r & 31))) << 2)] = v;
    }
    const float b0 = b_exp[e * DIM + tid];
    const float b1 = b_exp[e * DIM + 64 + tid];
    __syncthreads();

    const int r0 = tid, r1 = tid + 64;
    const int sw0 = r0 & 31, sw1 = r1 & 31;
    const int sBeg = slice * 1024, sEnd = sBeg + 1024;
    for (int base = sBeg; base < sEnd; base += 64) {
        int pid = pos_ids[base + tid];
        unsigned long long m = __ballot(pid == e);
        while (m) {
            int t = __builtin_ctzll(m);
            m &= m - 1;
            int s = base + t;
            const float4* ev = (const float4*)(embs + (size_t)s * DIM);
            float a0 = b0, a1 = b1;
            #pragma unroll
            for (int j4 = 0; j4 < 32; ++j4) {
                float4 x  = ev[j4];                                    // bcast (L1)
                float4 w0 = *(const float4*)&Wl[r0 * DIM + ((j4 ^ sw0) << 2)];
                float4 w1 = *(const float4*)&Wl[r1 * DIM + ((j4 ^ sw1) << 2)];
                a0 = fmaf(w0.x,x.x,fmaf(w0.y,x.y,fmaf(w0.z,x.z,fmaf(w0.w,x.w,a0))));
                a1 = fmaf(w1.x,x.x,fmaf(w1.y,x.y,fmaf(w1.z,x.z,fmaf(w1.w,x.w,a1))));
            }
            float* zp = xg + (size_t)s * NGATE;
            zp[tid]      = a0;
            zp[tid + 64] = a1;
        }
    }
}

// ---------------------------------------------------------------------------
// K1b: xg[s] = W_ih @ z[s] + b_ih + b_hh   (z read from xg[s*512+0..128))
// grid = 256 blocks * 32 tokens, 256 threads
// ---------------------------------------------------------------------------
__global__ __launch_bounds__(256) void gate_gemm(
    const float* __restrict__ W_ih, const float* __restrict__ b_ih,
    const float* __restrict__ b_hh, float* __restrict__ xg)
{
    __shared__ float zl[32 * DIM];    // 16KB, XOR-swizzled by token
    __shared__ float Wl[64 * DIM];    // 32KB, XOR-swizzled by row
    const int tid = threadIdx.x;
    const int s0  = blockIdx.x * 32;

    #pragma unroll
    for (int it = 0; it < 4; ++it) {
        int idx = it * 256 + tid;     // 0..1023 float4s
        int tok = idx >> 5, c4 = idx & 31;
        float4 v = *(const float4*)(xg + ((size_t)(s0 + tok)) * NGATE + (c4 << 2));
        *(float4*)&zl[tok * DIM + (((c4 ^ (tok & 31))) << 2)] = v;
    }
    __syncthreads();

    const int lane = tid & 63;        // row within 64-row chunk
    const int tg   = tid >> 6;        // token group 0..3 -> tokens tg*8..+8
    const int swr  = lane & 31;

    for (int ch = 0; ch < 8; ++ch) {
        #pragma unroll
        for (int it = 0; it < 8; ++it) {
            int idx = it * 256 + tid; // 0..2047 float4s
            int r = idx >> 5, c4 = idx & 31;
            float4 v = *(const float4*)(W_ih + ((size_t)(ch * 64 + r)) * DIM + (c4 << 2));
            *(float4*)&Wl[r * DIM + ((c4 ^ (r & 31)) << 2)] = v;
        }
        __syncthreads();

        const int row = ch * 64 + lane;
        const float bias = b_ih[row] + b_hh[row];
        float acc[8];
        #pragma unroll
        for (int k = 0; k < 8; ++k) acc[k] = bias;
        #pragma unroll 8
        for (int j4 = 0; j4 < 32; ++j4) {
            float4 w = *(const float4*)&Wl[lane * DIM + ((j4 ^ swr) << 2)];
            #pragma unroll
            for (int k = 0; k < 8; ++k) {
                int tok = tg * 8 + k;
                float4 z = *(const float4*)&zl[tok * DIM + ((j4 ^ (tok & 31)) << 2)];
                acc[k] = fmaf(w.x,z.x,fmaf(w.y,z.y,fmaf(w.z,z.z,fmaf(w.w,z.w,acc[k]))));
            }
        }
        #pragma unroll
        for (int k = 0; k < 8; ++k) {
            int tok = tg * 8 + k;
            xg[((size_t)(s0 + tok)) * NGATE + row] = acc[k];
        }
        __syncthreads();   // before next chunk overwrites Wl
    }
}

// ---------------------------------------------------------------------------
// K2: LSTM scan + max-pool. ONE block, 256 threads (4 waves, 1 wave/SIMD).
// ---------------------------------------------------------------------------
__global__ __launch_bounds__(256, 1) void lstm_scan(
    const float* __restrict__ xg, const float* __restrict__ W_hh,
    float* __restrict__ out)
{
    const int G = threadIdx.x;     // 0..255
    const int L = G & 63;
    const int row0 = G;            // i (0..127) / f (128..255)
    const int row1 = G + 256;      // g (256..383) / o (384..511)

    __shared__ float gbuf[2][NGATE];

    // W_hh rows packed to half2: 64+64 regs -> fits arch VGPR file (no AGPR trip)
    half2v wp0[64], wp1[64];
    {
        const float4* r0 = (const float4*)(W_hh + (size_t)row0 * DIM);
        const float4* r1 = (const float4*)(W_hh + (size_t)row1 * DIM);
        #pragma unroll
        for (int k = 0; k < 32; ++k) {
            float4 a = r0[k];
            wp0[2*k+0] = pack2(a.x, a.y);
            wp0[2*k+1] = pack2(a.z, a.w);
            float4 b = r1[k];
            wp1[2*k+0] = pack2(b.x, b.y);
            wp1[2*k+1] = pack2(b.z, b.w);
        }
    }

    float2 hv  = {0.0f, 0.0f};
    float2 cv  = {0.0f, 0.0f};
    float2 hmx = {-INFINITY, -INFINITY};
    int hp = 0;   // packed half2 (h[2L], h[2L+1]); zero bits == (0,0)

    // xg pipeline, distance 2 (covers L2/L3 latency)
    float x0a = xg[row0],         x1a = xg[row1];
    float x0b = xg[NGATE + row0], x1b = xg[NGATE + row1];

    for (int t = 0; t < SEQ; ++t) {
        const int tn = (t + 2 < SEQ) ? (t + 2) : (SEQ - 1);
        const float x0n = xg[(size_t)tn * NGATE + row0];
        const float x1n = xg[(size_t)tn * NGATE + row1];

        // gates pre-activation: dot(W_hh[row], h) via packed-fp16 dot2, fp32 acc
        float a0a = 0.0f, a0b = 0.0f, a1a = 0.0f, a1b = 0.0f;
        #pragma unroll
        for (int j = 0; j < 64; j += 2) {
            int si0 = __builtin_amdgcn_readlane(hp, j);
            int si1 = __builtin_amdgcn_readlane(hp, j + 1);
            half2v s0 = __builtin_bit_cast(half2v, si0);
            half2v s1 = __builtin_bit_cast(half2v, si1);
            a0a = __builtin_amdgcn_fdot2(wp0[j],     s0, a0a, false);
            a1a = __builtin_amdgcn_fdot2(wp1[j],     s0, a1a, false);
            a0b = __builtin_amdgcn_fdot2(wp0[j + 1], s1, a0b, false);
            a1b = __builtin_amdgcn_fdot2(wp1[j + 1], s1, a1b, false);
        }
        const float p0 = x0a + (a0a + a0b);
        const float p1 = x1a + (a1a + a1b);

        const float act0 = sigm_fast(p0);                              // i or f
        const float act1 = (G < 128) ? tanh_fast(p1) : sigm_fast(p1);  // g or o

        float* gb = gbuf[t & 1];
        gb[row0] = act0;
        gb[row1] = act1;
        __syncthreads();   // single barrier per step (double-buffered gbuf)

        const float2 iv = *(const float2*)(gb + 0   + 2 * L);
        const float2 fv = *(const float2*)(gb + 128 + 2 * L);
        const float2 gv = *(const float2*)(gb + 256 + 2 * L);
        const float2 ov = *(const float2*)(gb + 384 + 2 * L);

        cv.x = fmaf(fv.x, cv.x, iv.x * gv.x);
        cv.y = fmaf(fv.y, cv.y, iv.y * gv.y);
        hv.x = ov.x * tanh_fast(cv.x);
        hv.y = ov.y * tanh_fast(cv.y);

        hmx.x = fmaxf(hmx.x, hv.x);
        hmx.y = fmaxf(hmx.y, hv.y);

        hp = __builtin_bit_cast(int, pack2(hv.x, hv.y));

        x0a = x0b; x1a = x1b; x0b = x0n; x1b = x1n;
    }

    if (G < 64) ((float2*)out)[L] = hmx;
}

// ---------------------------------------------------------------------------
extern "C" void kernel_launch(void* const* d_in, const int* in_sizes, int n_in,
                              void* d_out, int out_size, void* d_ws, size_t ws_size,
                              hipStream_t stream)
{
    const float* embs  = (const float*)d_in[0];
    const int*   pos   = (const int*)  d_in[1];
    const float* W_exp = (const float*)d_in[2];
    const float* b_exp = (const float*)d_in[3];
    const float* W_ih  = (const float*)d_in[4];
    const float* W_hh  = (const float*)d_in[5];
    const float* b_ih  = (const float*)d_in[6];
    const float* b_hh  = (const float*)d_in[7];
    float* out = (float*)d_out;
    float* xg  = (float*)d_ws;   // [SEQ][512] fp32 = 16 MB (z lives in cols 0..127)

    expert_gemv<<<dim3(NEXP * 8), 64, 0, stream>>>(embs, pos, W_exp, b_exp, xg);
    gate_gemm  <<<dim3(256), 256, 0, stream>>>(W_ih, b_ih, b_hh, xg);
    lstm_scan  <<<dim3(1), 256, 0, stream>>>(xg, W_hh, out);
}